// Round 1
// baseline (619.090 us; speedup 1.0000x reference)
//
#include <hip/hip_runtime.h>
#include <hip/hip_bf16.h>

// Problem: out[M,N] = data[M,K] @ (weight*mask)[N,K]^T + bias[N]
// M = 4*2048 = 8192, N = 4096, K = 4096, all fp32 in/out.
// Strategy: cast A and W*mask to bf16 in d_ws, then m97-style 128x128-tile
// MFMA GEMM (16x16x32 bf16, BK=32, global_load_lds width=16, 4 waves/block).

#define M_TOT 8192
#define N_TOT 4096
#define K_TOT 4096

typedef __attribute__((ext_vector_type(8))) short short8;
typedef __attribute__((ext_vector_type(4))) float floatx4;

// ---- fp32 -> bf16 with round-to-nearest-even (manual, no NaN concern here) ----
__device__ inline unsigned short f2bf(float f) {
    unsigned int u = __builtin_bit_cast(unsigned int, f);
    u += 0x7fffu + ((u >> 16) & 1u);
    return (unsigned short)(u >> 16);
}

// data[M*K] fp32 -> bf16
__global__ __launch_bounds__(256) void cast_data_kernel(const float4* __restrict__ in,
                                                        ushort4* __restrict__ out) {
    int i = blockIdx.x * 256 + threadIdx.x;   // grid covers exactly M*K/4
    float4 f = in[i];
    ushort4 o;
    o.x = f2bf(f.x); o.y = f2bf(f.y); o.z = f2bf(f.z); o.w = f2bf(f.w);
    out[i] = o;
}

// (weight * mask)[N*K] fp32 -> bf16
__global__ __launch_bounds__(256) void cast_w_kernel(const float4* __restrict__ w,
                                                     const float4* __restrict__ m,
                                                     ushort4* __restrict__ out) {
    int i = blockIdx.x * 256 + threadIdx.x;   // grid covers exactly N*K/4
    float4 a = w[i];
    float4 b = m[i];
    ushort4 o;
    o.x = f2bf(a.x * b.x); o.y = f2bf(a.y * b.y);
    o.z = f2bf(a.z * b.z); o.w = f2bf(a.w * b.w);
    out[i] = o;
}

// ---- async global->LDS, 16B per lane ----
__device__ inline void load_lds16(const unsigned short* g, unsigned short* l) {
    __builtin_amdgcn_global_load_lds(
        (__attribute__((address_space(1))) void*)(const_cast<unsigned short*>(g)),
        (__attribute__((address_space(3))) void*)(l),
        16, 0, 0);
}

// C[M,N] = A[M,K] * W[N,K]^T + bias, A/W bf16, C fp32.
// Block = 256 threads (4 waves), tile 128x128, BK=32.
// Wave w handles 64x64 quadrant (w>>1, w&1); 4x4 grid of 16x16x32 MFMAs.
__global__ __launch_bounds__(256) void gemm_bt_kernel(const unsigned short* __restrict__ A,
                                                      const unsigned short* __restrict__ W,
                                                      const float* __restrict__ bias,
                                                      float* __restrict__ out) {
    __shared__ __align__(16) unsigned short As[128 * 32];
    __shared__ __align__(16) unsigned short Bs[128 * 32];

    const int t = threadIdx.x;
    const int m0 = blockIdx.y * 128;
    const int n0 = blockIdx.x * 128;

    // Staging: 128x32 bf16 tile = 8192 B = 512 chunks of 16 B; 256 threads x 2 chunks.
    // Chunk c -> LDS elems [c*8, c*8+8) ; global row = c>>2, k-offset = (c&3)*8.
    // LDS dst is linear in thread order (global_load_lds needs base + lane*16).
    const unsigned short* ag0 = A + (m0 + (t >> 2)) * K_TOT + ((t & 3) * 8);
    const unsigned short* ag1 = ag0 + 64 * K_TOT;
    const unsigned short* bg0 = W + (n0 + (t >> 2)) * K_TOT + ((t & 3) * 8);
    const unsigned short* bg1 = bg0 + 64 * K_TOT;
    unsigned short* al0 = As + t * 8;
    unsigned short* al1 = As + t * 8 + 2048;
    unsigned short* bl0 = Bs + t * 8;
    unsigned short* bl1 = Bs + t * 8 + 2048;

    const int wave = t >> 6;
    const int lane = t & 63;
    const int quad = lane >> 4;     // lane>>4 in [0,4)
    const int row16 = lane & 15;    // position within 16-wide dim
    const int wm = (wave >> 1) * 64;
    const int wn = (wave & 1) * 64;

    floatx4 acc[4][4];
#pragma unroll
    for (int i = 0; i < 4; i++)
#pragma unroll
        for (int j = 0; j < 4; j++) {
            floatx4 z = {0.0f, 0.0f, 0.0f, 0.0f};
            acc[i][j] = z;
        }

    for (int kt = 0; kt < K_TOT / 32; ++kt) {
        load_lds16(ag0, al0);
        load_lds16(ag1, al1);
        load_lds16(bg0, bl0);
        load_lds16(bg1, bl1);
        ag0 += 32; ag1 += 32; bg0 += 32; bg1 += 32;
        __syncthreads();   // drains vmcnt: LDS tiles ready

        short8 af[4], bf[4];
#pragma unroll
        for (int i = 0; i < 4; i++) {
            // A frag: lane holds A[m = row16][k = quad*8 + j], K-contiguous in LDS
            af[i] = *(const short8*)(As + (wm + i * 16 + row16) * 32 + quad * 8);
            // B frag (B^T form): lane holds W[n = row16][k = quad*8 + j]
            bf[i] = *(const short8*)(Bs + (wn + i * 16 + row16) * 32 + quad * 8);
        }
#pragma unroll
        for (int i = 0; i < 4; i++)
#pragma unroll
            for (int j = 0; j < 4; j++)
                acc[i][j] = __builtin_amdgcn_mfma_f32_16x16x32_bf16(af[i], bf[j], acc[i][j], 0, 0, 0);
        __syncthreads();   // compute done before next stage overwrites LDS
    }

    // Epilogue: C/D layout (16x16x32): col = lane&15, row = (lane>>4)*4 + reg
#pragma unroll
    for (int i = 0; i < 4; i++) {
        const int gm = m0 + wm + i * 16 + quad * 4;
#pragma unroll
        for (int j = 0; j < 4; j++) {
            const int gn = n0 + wn + j * 16 + row16;
            const float b = bias[gn];
            float* o = out + gm * N_TOT + gn;
#pragma unroll
            for (int r = 0; r < 4; r++)
                o[r * N_TOT] = acc[i][j][r] + b;
        }
    }
}

extern "C" void kernel_launch(void* const* d_in, const int* in_sizes, int n_in,
                              void* d_out, int out_size, void* d_ws, size_t ws_size,
                              hipStream_t stream) {
    const float* data   = (const float*)d_in[0];   // [4,2048,4096]
    const float* weight = (const float*)d_in[1];   // [4096,4096]
    const float* w_mask = (const float*)d_in[2];   // [4096,4096]
    const float* bias_p = (const float*)d_in[3];   // [4096]
    float* out = (float*)d_out;

    // Workspace layout: A_bf16 [M*K] then W_bf16 [N*K]  (96 MB total)
    unsigned short* a_bf = (unsigned short*)d_ws;
    unsigned short* w_bf = a_bf + (size_t)M_TOT * K_TOT;

    // Cast kernels (exact grids, no tails)
    cast_data_kernel<<<(M_TOT * K_TOT) / (256 * 4), 256, 0, stream>>>(
        (const float4*)data, (ushort4*)a_bf);
    cast_w_kernel<<<(N_TOT * K_TOT) / (256 * 4), 256, 0, stream>>>(
        (const float4*)weight, (const float4*)w_mask, (ushort4*)w_bf);

    dim3 grid(N_TOT / 128, M_TOT / 128);   // (32, 64)
    gemm_bt_kernel<<<grid, 256, 0, stream>>>(a_bf, w_bf, bias_p, out);
}

// Round 3
// 611.424 us; speedup vs baseline: 1.0125x; 1.0125x over previous
//
#include <hip/hip_runtime.h>
#include <hip/hip_bf16.h>

// Problem: out[M,N] = data[M,K] @ (weight*mask)[N,K]^T + bias[N]
// M = 4*2048 = 8192, N = 4096, K = 4096, all fp32 in/out.
// R3: cast path reverted to R1's exact two-kernel form (proven pass; R2's
// fused grid-stride cast coincided with a post-timing divergence AND bought
// zero time — the non-GEMM ~267us is mostly harness restore/poison overhead).
// GEMM change: XOR bank-swizzle on the LDS k-chunk slot to kill the 8-way
// ds_read_b128 bank conflict (SQ_LDS_BANK_CONFLICT 3.36e7 in R1).

#define M_TOT 8192
#define N_TOT 4096
#define K_TOT 4096

typedef __attribute__((ext_vector_type(8))) short short8;
typedef __attribute__((ext_vector_type(4))) float floatx4;

// ---- fp32 -> bf16 round-to-nearest-even ----
__device__ inline unsigned short f2bf(float f) {
    unsigned int u = __builtin_bit_cast(unsigned int, f);
    u += 0x7fffu + ((u >> 16) & 1u);
    return (unsigned short)(u >> 16);
}

// data[M*K] fp32 -> bf16  (exact grid, one float4 per thread) — R1 verbatim
__global__ __launch_bounds__(256) void cast_data_kernel(const float4* __restrict__ in,
                                                        ushort4* __restrict__ out) {
    int i = blockIdx.x * 256 + threadIdx.x;
    float4 f = in[i];
    ushort4 o;
    o.x = f2bf(f.x); o.y = f2bf(f.y); o.z = f2bf(f.z); o.w = f2bf(f.w);
    out[i] = o;
}

// (weight * mask)[N*K] fp32 -> bf16 — R1 verbatim
__global__ __launch_bounds__(256) void cast_w_kernel(const float4* __restrict__ w,
                                                     const float4* __restrict__ m,
                                                     ushort4* __restrict__ out) {
    int i = blockIdx.x * 256 + threadIdx.x;
    float4 a = w[i];
    float4 b = m[i];
    ushort4 o;
    o.x = f2bf(a.x * b.x); o.y = f2bf(a.y * b.y);
    o.z = f2bf(a.z * b.z); o.w = f2bf(a.w * b.w);
    out[i] = o;
}

// ---- async global->LDS, 16B per lane ----
__device__ inline void load_lds16(const unsigned short* g, unsigned short* l) {
    __builtin_amdgcn_global_load_lds(
        (__attribute__((address_space(1))) void*)(const_cast<unsigned short*>(g)),
        (__attribute__((address_space(3))) void*)(l),
        16, 0, 0);
}

// C[M,N] = A[M,K] * W[N,K]^T + bias, A/W bf16, C fp32.
// Block = 256 threads (4 waves), tile 128x128, BK=32.
// LDS layout: row r (64 B = 4 chunks of 16 B); slot s of row r holds global
// k-chunk (s ^ ((r>>1)&3)). Staging applies the swizzle by offsetting each
// lane's GLOBAL source pointer (LDS dst stays linear, as global_load_lds
// requires); readers XOR their quad with (row16>>1)&3.
// Bank math: start bank = 16*(r&1) + 4*(quad ^ ((r>>1)&3)) -> rows 0..7
// cover all 8 bank-quads; rows 8..15 alias 2-way (free).
__global__ __launch_bounds__(256) void gemm_bt_kernel(const unsigned short* __restrict__ A,
                                                      const unsigned short* __restrict__ W,
                                                      const float* __restrict__ bias,
                                                      float* __restrict__ out) {
    __shared__ __align__(16) unsigned short As[128 * 32];
    __shared__ __align__(16) unsigned short Bs[128 * 32];

    const int t = threadIdx.x;
    const int m0 = blockIdx.y * 128;
    const int n0 = blockIdx.x * 128;

    // Staging: chunk t -> (row = t>>2, slot = t&3); source k-chunk = slot ^ ((row>>1)&3)
    // = (t&3) ^ ((t>>3)&3). Same formula holds for the +64-row chunk (row base 64
    // is a multiple of 16, so (r>>1)&3 is unchanged).
    const int kc = ((t & 3) ^ ((t >> 3) & 3));
    const unsigned short* ag0 = A + (m0 + (t >> 2)) * K_TOT + kc * 8;
    const unsigned short* ag1 = ag0 + 64 * K_TOT;
    const unsigned short* bg0 = W + (n0 + (t >> 2)) * K_TOT + kc * 8;
    const unsigned short* bg1 = bg0 + 64 * K_TOT;
    unsigned short* al0 = As + t * 8;
    unsigned short* al1 = As + t * 8 + 2048;
    unsigned short* bl0 = Bs + t * 8;
    unsigned short* bl1 = Bs + t * 8 + 2048;

    const int wave = t >> 6;
    const int lane = t & 63;
    const int quad = lane >> 4;     // k-chunk wanted by this lane
    const int row16 = lane & 15;    // position within 16-wide m/n dim
    const int wm = (wave >> 1) * 64;
    const int wn = (wave & 1) * 64;
    // swizzle factor for this lane's row (row base is always a multiple of 16)
    const int xs = (row16 >> 1) & 3;
    const int slot = (quad ^ xs) * 8;   // ushort offset of the k-chunk within the row

    floatx4 acc[4][4];
#pragma unroll
    for (int i = 0; i < 4; i++)
#pragma unroll
        for (int j = 0; j < 4; j++) {
            floatx4 z = {0.0f, 0.0f, 0.0f, 0.0f};
            acc[i][j] = z;
        }

    for (int kt = 0; kt < K_TOT / 32; ++kt) {
        load_lds16(ag0, al0);
        load_lds16(ag1, al1);
        load_lds16(bg0, bl0);
        load_lds16(bg1, bl1);
        ag0 += 32; ag1 += 32; bg0 += 32; bg1 += 32;
        __syncthreads();   // drains vmcnt: LDS tiles ready

        short8 af[4], bf[4];
#pragma unroll
        for (int i = 0; i < 4; i++) {
            af[i] = *(const short8*)(As + (wm + i * 16 + row16) * 32 + slot);
            bf[i] = *(const short8*)(Bs + (wn + i * 16 + row16) * 32 + slot);
        }
#pragma unroll
        for (int i = 0; i < 4; i++)
#pragma unroll
            for (int j = 0; j < 4; j++)
                acc[i][j] = __builtin_amdgcn_mfma_f32_16x16x32_bf16(af[i], bf[j], acc[i][j], 0, 0, 0);
        __syncthreads();   // compute done before next stage overwrites LDS
    }

    // Epilogue: C/D layout (16x16x32): col = lane&15, row = (lane>>4)*4 + reg
    float bb[4];
#pragma unroll
    for (int j = 0; j < 4; j++)
        bb[j] = bias[n0 + wn + j * 16 + row16];

#pragma unroll
    for (int i = 0; i < 4; i++) {
        const int gm = m0 + wm + i * 16 + quad * 4;
#pragma unroll
        for (int j = 0; j < 4; j++) {
            const int gn = n0 + wn + j * 16 + row16;
            float* o = out + gm * N_TOT + gn;
#pragma unroll
            for (int r = 0; r < 4; r++)
                o[r * N_TOT] = acc[i][j][r] + bb[j];
        }
    }
}

extern "C" void kernel_launch(void* const* d_in, const int* in_sizes, int n_in,
                              void* d_out, int out_size, void* d_ws, size_t ws_size,
                              hipStream_t stream) {
    const float* data   = (const float*)d_in[0];   // [4,2048,4096]
    const float* weight = (const float*)d_in[1];   // [4096,4096]
    const float* w_mask = (const float*)d_in[2];   // [4096,4096]
    const float* bias_p = (const float*)d_in[3];   // [4096]
    float* out = (float*)d_out;

    // Workspace layout: A_bf16 [M*K] then W_bf16 [N*K]  (96 MB total)
    unsigned short* a_bf = (unsigned short*)d_ws;
    unsigned short* w_bf = a_bf + (size_t)M_TOT * K_TOT;

    cast_data_kernel<<<(M_TOT * K_TOT) / (256 * 4), 256, 0, stream>>>(
        (const float4*)data, (ushort4*)a_bf);
    cast_w_kernel<<<(N_TOT * K_TOT) / (256 * 4), 256, 0, stream>>>(
        (const float4*)weight, (const float4*)w_mask, (ushort4*)w_bf);

    dim3 grid(N_TOT / 128, M_TOT / 128);   // (32, 64)
    gemm_bt_kernel<<<grid, 256, 0, stream>>>(a_bf, w_bf, bias_p, out);
}